// Round 2
// baseline (1007.629 us; speedup 1.0000x reference)
//
#include <hip/hip_runtime.h>
#include <hip/hip_bf16.h>
#include <math.h>

// All reference tensors are float32 (setup_inputs uses jnp.float32):
// inputs are const float*, d_out is float*. Round-1 NaN was caused by
// casting fp32 data to bf16.

// ---------------------------------------------------------------------------
// Pooling: one 64-lane wave per (batch,channel) row; mean over rowlen elems.
// Scalar variant (any rowlen).
// ---------------------------------------------------------------------------
__global__ void pool_rows_kernel(const float* __restrict__ src, float* __restrict__ dst,
                                 int rows, int rowlen, float inv) {
    int gid  = blockIdx.x * blockDim.x + threadIdx.x;
    int wave = gid >> 6;
    int lane = gid & 63;
    if (wave >= rows) return;
    const float* p = src + (size_t)wave * rowlen;
    float s = 0.f;
    for (int k = lane; k < rowlen; k += 64) s += p[k];
    #pragma unroll
    for (int off = 32; off > 0; off >>= 1) s += __shfl_down(s, off, 64);
    if (lane == 0) dst[wave] = s * inv;
}

// Vectorized variant: rowlen % 4 == 0, float4 loads (16 B/lane).
__global__ void pool_rows_v4_kernel(const float* __restrict__ src, float* __restrict__ dst,
                                    int rows, int rowlen4, float inv) {
    int gid  = blockIdx.x * blockDim.x + threadIdx.x;
    int wave = gid >> 6;
    int lane = gid & 63;
    if (wave >= rows) return;
    const float4* p = (const float4*)(src + (size_t)wave * rowlen4 * 4);
    float s = 0.f;
    for (int k = lane; k < rowlen4; k += 64) {
        float4 v = p[k];
        s += (v.x + v.y) + (v.z + v.w);
    }
    #pragma unroll
    for (int off = 32; off > 0; off >>= 1) s += __shfl_down(s, off, 64);
    if (lane == 0) dst[wave] = s * inv;
}

// ---------------------------------------------------------------------------
// Naive FC: one thread per output element. X fp32 [M,K], W fp32 [K,N] row-major.
// Consecutive threads share m, consecutive n -> W rows coalesced, X broadcast.
// ---------------------------------------------------------------------------
__global__ void fc_kernel(const float* __restrict__ X, const float* __restrict__ W,
                          const float* __restrict__ bias, float* __restrict__ Y,
                          int M, int K, int N, int do_relu) {
    int idx = blockIdx.x * blockDim.x + threadIdx.x;
    if (idx >= M * N) return;
    int m = idx / N, n = idx - m * N;
    const float* x = X + (size_t)m * K;
    float acc = bias[n];
    #pragma unroll 4
    for (int k = 0; k < K; ++k) acc += x[k] * W[(size_t)k * N + n];
    if (do_relu) acc = fmaxf(acc, 0.f);
    Y[idx] = acc;
}

// ---------------------------------------------------------------------------
// top-2 of 5 gate logits + softmax over the two values; also emits fp32
// outputs (gate_logits, topi-as-float, w). jax.lax.top_k tie rule: lower
// index wins on equality (strict > comparisons preserve that).
// ---------------------------------------------------------------------------
__global__ void top2_kernel(const float* __restrict__ gl, int* __restrict__ topi,
                            float* __restrict__ wsm,
                            float* __restrict__ out_gl, float* __restrict__ out_topi,
                            float* __restrict__ out_w, int B) {
    int b = blockIdx.x * blockDim.x + threadIdx.x;
    if (b >= B) return;
    float v[5];
    #pragma unroll
    for (int i = 0; i < 5; ++i) v[i] = gl[b * 5 + i];
    int i0 = 0;
    #pragma unroll
    for (int i = 1; i < 5; ++i) if (v[i] > v[i0]) i0 = i;
    int i1 = -1;
    #pragma unroll
    for (int i = 0; i < 5; ++i) {
        if (i == i0) continue;
        if (i1 < 0 || v[i] > v[i1]) i1 = i;
    }
    float m  = v[i0];  // v[i0] >= v[i1]
    float e0 = __expf(v[i0] - m), e1 = __expf(v[i1] - m);
    float inv = 1.f / (e0 + e1);
    float w0 = e0 * inv, w1 = e1 * inv;
    topi[b * 2] = i0; topi[b * 2 + 1] = i1;
    wsm[b * 2] = w0;  wsm[b * 2 + 1] = w1;
    #pragma unroll
    for (int i = 0; i < 5; ++i) out_gl[b * 5 + i] = v[i];
    out_topi[b * 2]     = (float)i0;
    out_topi[b * 2 + 1] = (float)i1;
    out_w[b * 2]     = w0;
    out_w[b * 2 + 1] = w1;
}

// ---------------------------------------------------------------------------
// Per-batch: compute the two SELECTED stage projections (Linear + LayerNorm +
// exact GELU) and accumulate the softmax-weighted mixture. Block = 512 threads
// (one per feature), one block per batch element.
// ---------------------------------------------------------------------------
struct ProjParams {
    const float* W[5];
    const float* bp[5];
    const float* g[5];
    const float* be[5];
    int K[5];
    int poff[5];
};

__global__ void proj_mix_kernel(ProjParams P, const float* __restrict__ pools,
                                const int* __restrict__ topi, const float* __restrict__ wsm,
                                float* __restrict__ mix) {
    const int b = blockIdx.x;
    const int f = threadIdx.x;           // 0..511
    __shared__ float sp[160];
    __shared__ float redS[8], redQ[8];
    __shared__ float s_mu, s_rstd;

    float acc = 0.f;
    for (int j = 0; j < 2; ++j) {
        __syncthreads();                 // protect sp / red reuse across iterations
        const int st = topi[b * 2 + j];
        const int K  = P.K[st];
        const float* p = pools + P.poff[st] + (size_t)b * K;
        if (f < K) sp[f] = p[f];
        __syncthreads();

        const float* W = P.W[st];
        float h = P.bp[st][f];
        for (int k = 0; k < K; ++k) h += sp[k] * W[(size_t)k * 512 + f];

        // LayerNorm over 512 features (ddof=0)
        float s = h, q = h * h;
        #pragma unroll
        for (int off = 32; off > 0; off >>= 1) {
            s += __shfl_down(s, off, 64);
            q += __shfl_down(q, off, 64);
        }
        const int lane = threadIdx.x & 63, wid = threadIdx.x >> 6;
        if (lane == 0) { redS[wid] = s; redQ[wid] = q; }
        __syncthreads();
        if (threadIdx.x == 0) {
            float ts = 0.f, tq = 0.f;
            #pragma unroll
            for (int i = 0; i < 8; ++i) { ts += redS[i]; tq += redQ[i]; }
            float mu  = ts * (1.f / 512.f);
            float var = tq * (1.f / 512.f) - mu * mu;
            s_mu   = mu;
            s_rstd = rsqrtf(var + 1e-5f);
        }
        __syncthreads();

        float x  = (h - s_mu) * s_rstd * P.g[st][f] + P.be[st][f];
        float ge = 0.5f * x * (1.f + erff(x * 0.70710678118654752f));
        acc += wsm[b * 2 + j] * ge;
    }
    mix[(size_t)b * 512 + f] = acc;
}

// ---------------------------------------------------------------------------
extern "C" void kernel_launch(void* const* d_in, const int* in_sizes, int n_in,
                              void* d_out, int out_size, void* d_ws, size_t ws_size,
                              hipStream_t stream) {
    const int B = 256, F = 512, H = 1024, C = 1000;

    const float* s1 = (const float*)d_in[0];
    const float* s2 = (const float*)d_in[1];
    const float* s3 = (const float*)d_in[2];
    const float* s4 = (const float*)d_in[3];
    const float* s5 = (const float*)d_in[4];
    const float* ff = (const float*)d_in[5];
    const float *Wp[5], *bp[5], *g[5], *be[5];
    for (int i = 0; i < 5; ++i) {
        Wp[i] = (const float*)d_in[6 + 4 * i];
        bp[i] = (const float*)d_in[7 + 4 * i];
        g[i]  = (const float*)d_in[8 + 4 * i];
        be[i] = (const float*)d_in[9 + 4 * i];
    }
    const float* Wg1 = (const float*)d_in[26]; const float* bg1 = (const float*)d_in[27];
    const float* Wg2 = (const float*)d_in[28]; const float* bg2 = (const float*)d_in[29];
    const float* Wg3 = (const float*)d_in[30]; const float* bg3 = (const float*)d_in[31];
    const float* Wc1 = (const float*)d_in[32]; const float* bc1 = (const float*)d_in[33];
    const float* Wc2 = (const float*)d_in[34]; const float* bc2 = (const float*)d_in[35];
    const float* Wc3 = (const float*)d_in[36]; const float* bc3 = (const float*)d_in[37];

    // ---- workspace layout (fp32 elements) ----
    float* ws = (float*)d_ws;
    const int Ks[5]   = {16, 24, 40, 80, 160};
    const int poff[5] = {0, 4096, 10240, 20480, 40960};      // B*K prefix sums
    float* pools   = ws;                                      // 81920
    float* gate_in = ws + 81920;                              // 245760
    float* g1h     = ws + 327680;                             // 262144
    float* g2h     = ws + 589824;                             // 131072
    float* glog    = ws + 720896;                             // 1280
    float* wsm     = ws + 722176;                             // 512
    int*   topi    = (int*)(ws + 722688);                     // 512
    float* mix     = ws + 723200;                             // 131072
    float* c1h     = ws + 854272;                             // 262144
    float* c2h     = ws + 1116416;                            // 131072

    float* out      = (float*)d_out;
    float* out_gl   = out + 256000;
    float* out_topi = out + 257280;
    float* out_w    = out + 257792;

    // ---- 1) pooling (wave per row) ----
    // float4 path where rowlen % 4 == 0 (112*112, 56*56, 28*28, 14*14)
    struct { const float* src; float* dst; int rows; int rowlen; } pl4[4] = {
        { s1, pools + poff[0], B * 16,  112 * 112 },
        { s2, pools + poff[1], B * 24,  56 * 56 },
        { s3, pools + poff[2], B * 40,  28 * 28 },
        { s4, pools + poff[3], B * 80,  14 * 14 },
    };
    for (int i = 0; i < 4; ++i) {
        int threads = pl4[i].rows * 64;
        int blocks  = (threads + 255) / 256;
        pool_rows_v4_kernel<<<blocks, 256, 0, stream>>>(pl4[i].src, pl4[i].dst, pl4[i].rows,
                                                        pl4[i].rowlen / 4, 1.f / pl4[i].rowlen);
    }
    {   // s5: [B,160,49], ff: [B,960,49]
        int rows = B * 160, threads = rows * 64;
        pool_rows_kernel<<<(threads + 255) / 256, 256, 0, stream>>>(s5, pools + poff[4], rows, 49, 1.f / 49.f);
        rows = B * 960; threads = rows * 64;
        pool_rows_kernel<<<(threads + 255) / 256, 256, 0, stream>>>(ff, gate_in, rows, 49, 1.f / 49.f);
    }

    // ---- 2) gate MLP ----
    fc_kernel<<<(B * H + 255) / 256, 256, 0, stream>>>(gate_in, Wg1, bg1, g1h, B, 960, H, 1);
    fc_kernel<<<(B * (H / 2) + 255) / 256, 256, 0, stream>>>(g1h, Wg2, bg2, g2h, B, H, H / 2, 1);
    fc_kernel<<<(B * 5 + 255) / 256, 256, 0, stream>>>(g2h, Wg3, bg3, glog, B, H / 2, 5, 0);

    // ---- 3) top-2 + softmax (+ fp32 outputs) ----
    top2_kernel<<<1, 256, 0, stream>>>(glog, topi, wsm, out_gl, out_topi, out_w, B);

    // ---- 4) selected projections + mixture ----
    ProjParams P;
    for (int i = 0; i < 5; ++i) {
        P.W[i] = Wp[i]; P.bp[i] = bp[i]; P.g[i] = g[i]; P.be[i] = be[i];
        P.K[i] = Ks[i]; P.poff[i] = poff[i];
    }
    proj_mix_kernel<<<B, 512, 0, stream>>>(P, pools, topi, wsm, mix);

    // ---- 5) classifier MLP ----
    fc_kernel<<<(B * H + 255) / 256, 256, 0, stream>>>(mix, Wc1, bc1, c1h, B, F, H, 1);
    fc_kernel<<<(B * (H / 2) + 255) / 256, 256, 0, stream>>>(c1h, Wc2, bc2, c2h, B, H, H / 2, 1);
    fc_kernel<<<(B * C + 255) / 256, 256, 0, stream>>>(c2h, Wc3, bc3, out, B, H / 2, C, 0);
}